// Round 4
// baseline (2311.532 us; speedup 1.0000x reference)
//
#include <hip/hip_runtime.h>

// Problem constants (from reference setup)
#define NB    128          // batches
#define NA    29           // atoms per batch
#define FD    64           // feature dim
#define NEDGE 812          // NA*(NA-1)
#define NITERS 2
#define NWAVE 16           // waves per fused block
#define TPB   1024         // threads per fused block

// d_ws layout (floats):
//   rpT : [NITERS][NB*NA][64][28]  (transposed edge projections, jr minor)
//   WT  : [3 arr][NITERS][2 p][2 sel][64 g][64 f]  (transposed dense weights)
#define RPROJ_PLANE (NB*NA*64*28)     // 6,651,904 floats per iteration
#define WT_OFF      (2*RPROJ_PLANE)   // 13,303,808
// total ws use: (13,303,808 + 98,304)*4 = 53.6 MB

// ---------------------------------------------------------------------------
// Kernel 0: transpose dense weights [it][p][sel][f][g] -> WT[arr][it][p][sel][g][f]
// 24 matrices of 64x64; grid 384*256 covers exactly 98304 elements.
// ---------------------------------------------------------------------------
__global__ __launch_bounds__(256) void transpose_w_kernel(
    const float* __restrict__ d1w, const float* __restrict__ d2w,
    const float* __restrict__ tdw, float* __restrict__ WT)
{
  const int idx = blockIdx.x*256 + threadIdx.x;
  const int mat = idx >> 12;            // 0..23
  const int rem = idx & 4095;
  const int g = rem >> 6, f = rem & 63;
  const float* src = (mat < 8) ? d1w : (mat < 16) ? d2w : tdw;
  const int m = mat & 7;                // it*4 + p*2 + sel
  WT[idx] = src[m*4096 + f*64 + g];
}

// ---------------------------------------------------------------------------
// Kernel 1: per-(batch,dst) block computes 28 edges' radial basis and projects
// through mp_basis_w for both iterations, writing TRANSPOSED:
//   rpT[it][(b*NA+n)*64 + g][jr]
// Per-edge transcendentals (log/cutoff) computed once and shared across k.
// ---------------------------------------------------------------------------
__global__ __launch_bounds__(256) void edge_rproj_kernel(
    const float* __restrict__ pos,      // [NB*NA][3]
    const float* __restrict__ Wb,       // [NITERS][64][64]
    float* __restrict__ rpT)
{
  __shared__ float elu[28], el1mu[28], efc[28];
  __shared__ float rads[28][FD];        // 7 KB
  const int bn  = blockIdx.x;           // b*NA + n
  const int b   = bn / NA, n = bn - b*NA;
  const int tid = threadIdx.x, lane = tid & 63, wv = tid >> 6;

  if (tid < 28) {
    const int jr = tid, j = jr + (jr >= n ? 1 : 0);
    const float dx = pos[(b*NA+j)*3+0] - pos[(b*NA+n)*3+0];
    const float dy = pos[(b*NA+j)*3+1] - pos[(b*NA+n)*3+1];
    const float dz = pos[(b*NA+j)*3+2] - pos[(b*NA+n)*3+2];
    const float r  = sqrtf(dx*dx + dy*dy + dz*dz + 1e-12f);
    const float u  = 1.0f/(1.0f + r);
    elu[jr]   = logf(u);
    el1mu[jr] = logf(fmaxf(1.0f - u, 1e-12f));
    const float x2 = (r*0.2f)*(r*0.2f);
    efc[jr] = (x2 < 1.0f) ? expf(1.0f - 1.0f/fmaxf(1.0f - x2, 1e-12f)) : 0.0f;
  }
  const float kk   = (float)lane;
  const float logc = lgammaf(64.0f) - lgammaf(kk + 1.0f) - lgammaf(64.0f - kk);
  __syncthreads();

  #pragma unroll
  for (int i = 0; i < 7; ++i) {
    const int e = wv*7 + i;             // this wave's own rows (same-wave RAW below)
    rads[e][lane] = expf(logc + kk*elu[e] + (63.0f - kk)*el1mu[e]) * efc[e];
  }
  // W columns for this lane's g, both iterations (128 VGPRs; 256-thread cap is 256)
  float wb0[64], wb1[64];
  #pragma unroll
  for (int k = 0; k < 64; ++k) { wb0[k] = Wb[k*FD + lane]; wb1[k] = Wb[4096 + k*FD + lane]; }
  __syncthreads();

  #pragma unroll
  for (int i = 0; i < 7; ++i) {
    const int jr = wv*7 + i;
    float a0 = 0.0f, a1 = 0.0f;
    #pragma unroll
    for (int k4 = 0; k4 < 16; ++k4) {
      const float4 rv = *(const float4*)&rads[jr][k4*4];   // broadcast read
      a0 += wb0[k4*4+0]*rv.x + wb0[k4*4+1]*rv.y + wb0[k4*4+2]*rv.z + wb0[k4*4+3]*rv.w;
      a1 += wb1[k4*4+0]*rv.x + wb1[k4*4+1]*rv.y + wb1[k4*4+2]*rv.z + wb1[k4*4+3]*rv.w;
    }
    const size_t o = ((size_t)bn*64 + lane)*28 + jr;
    rpT[o] = a0;
    rpT[RPROJ_PLANE + o] = a1;
  }
}

// ---------------------------------------------------------------------------
// Generic 20-path Clebsch-Gordan tensor product at one feature index.
// ---------------------------------------------------------------------------
__device__ __forceinline__ void tp20(const float* a, const float* bb,
                                     const float* w, float* o)
{
  #pragma unroll
  for (int p1 = 0; p1 < 2; ++p1) {
    #pragma unroll
    for (int p2 = 0; p2 < 2; ++p2) {
      const float* w5 = w + 5*(2*p1 + p2);
      const float s1 = a[p1*4+0], x1 = a[p1*4+1], y1 = a[p1*4+2], z1 = a[p1*4+3];
      const float s2 = bb[p2*4+0], x2 = bb[p2*4+1], y2 = bb[p2*4+2], z2 = bb[p2*4+3];
      const int so = (p1 == p2) ? 0 : 4;   // dest parity for T1..T4
      const int vo = 4 - so;               // dest parity for T5 (cross)
      o[so+0] += w5[0]*(s1*s2) + w5[3]*(x1*x2 + y1*y2 + z1*z2);
      o[so+1] += w5[1]*(s1*x2) + w5[2]*(x1*s2);
      o[so+2] += w5[1]*(s1*y2) + w5[2]*(y1*s2);
      o[so+3] += w5[1]*(s1*z2) + w5[2]*(z1*s2);
      o[vo+1] += w5[4]*(y1*z2 - z1*y2);
      o[vo+2] += w5[4]*(z1*x2 - x1*z2);
      o[vo+3] += w5[4]*(x1*y2 - y1*x2);
    }
  }
}

// ---------------------------------------------------------------------------
// Parity-blocked dense using TRANSPOSED weights: thread g float4-loads its
// weight column (contiguous [g][f]) into 16 wf registers up front (all loads
// in flight together), then FMAs against LDS inputs.
// WTm points at WT[arr][it] (4 matrices of [64][64]).
// ---------------------------------------------------------------------------
__device__ __forceinline__ void dense29T(const float (*in)[8][FD],
                                         const float* __restrict__ WTm,
                                         const float* __restrict__ bias,
                                         int a16, int g, float r[2][8])
{
  #pragma unroll
  for (int p = 0; p < 2; ++p) {
    // ---- sel 0 (scalar channel)
    {
      const float* w = WTm + (p*2+0)*4096 + g*64;
      float4 wf[16];
      #pragma unroll
      for (int q = 0; q < 16; ++q) wf[q] = *(const float4*)&w[q*4];
      const float bsv = bias ? bias[p*64 + g] : 0.0f;
      float acc[2] = {bsv, bsv};
      #pragma unroll
      for (int f4 = 0; f4 < 16; ++f4) {
        #pragma unroll
        for (int t = 0; t < 2; ++t) {
          const int n = a16 + 16*t;
          if (n >= NA) continue;
          const float4 xv = *(const float4*)&in[n][p*4+0][f4*4];
          acc[t] += wf[f4].x*xv.x + wf[f4].y*xv.y + wf[f4].z*xv.z + wf[f4].w*xv.w;
        }
      }
      #pragma unroll
      for (int t = 0; t < 2; ++t) r[t][p*4+0] = acc[t];
    }
    // ---- sel 1 (vector channels, 3 components share weights)
    {
      const float* w = WTm + (p*2+1)*4096 + g*64;
      float4 wf[16];
      #pragma unroll
      for (int q = 0; q < 16; ++q) wf[q] = *(const float4*)&w[q*4];
      float a1[2] = {0,0}, a2[2] = {0,0}, a3[2] = {0,0};
      #pragma unroll
      for (int f4 = 0; f4 < 16; ++f4) {
        #pragma unroll
        for (int t = 0; t < 2; ++t) {
          const int n = a16 + 16*t;
          if (n >= NA) continue;
          const float4 xa = *(const float4*)&in[n][p*4+1][f4*4];
          const float4 xb = *(const float4*)&in[n][p*4+2][f4*4];
          const float4 xc = *(const float4*)&in[n][p*4+3][f4*4];
          a1[t] += wf[f4].x*xa.x + wf[f4].y*xa.y + wf[f4].z*xa.z + wf[f4].w*xa.w;
          a2[t] += wf[f4].x*xb.x + wf[f4].y*xb.y + wf[f4].z*xb.z + wf[f4].w*xb.w;
          a3[t] += wf[f4].x*xc.x + wf[f4].y*xc.y + wf[f4].z*xc.z + wf[f4].w*xc.w;
        }
      }
      #pragma unroll
      for (int t = 0; t < 2; ++t) {
        r[t][p*4+1] = a1[t]; r[t][p*4+2] = a2[t]; r[t][p*4+3] = a3[t];
      }
    }
  }
}

// ---------------------------------------------------------------------------
// Kernel 2: whole model for one batch per block. 1024 threads = 16 waves.
// Thread (a16 = tid>>6, g = tid&63) owns feature column g of atoms {a16, a16+16}.
// ---------------------------------------------------------------------------
__global__ __launch_bounds__(TPB) void fused_model_kernel(
    const int*   __restrict__ Z,        // [NB*NA]
    const float* __restrict__ pos,      // [NB*NA][3]
    const float* __restrict__ Ef,       // [NB][3]
    const float* __restrict__ embed,    // [MAXZ][FD]
    const float* __restrict__ mp_tp_w,  // [NITERS][20][FD]
    const float* __restrict__ WT,       // transposed dense weights (ws)
    const float* __restrict__ d1b,      // [NITERS][2][FD]
    const float* __restrict__ d2b,
    const float* __restrict__ tens_w,   // [NITERS][20][FD]
    const float* __restrict__ td_tp_w,  // [NITERS][20][FD]
    const float* __restrict__ out_w,    // [FD]
    const float* __restrict__ ebias,    // [MAXZ]
    const float* __restrict__ rpT,      // transposed rproj (ws)
    float* __restrict__ out)            // [NB]
{
  __shared__ float xs[NA][8][FD];     // node state x           (59392 B)
  __shared__ float ts[NA][8][FD];     // dense intermediate     (59392 B)
  __shared__ float us[NEDGE][3];      // unit vectors           ( 9744 B)
  __shared__ float posb[NA][3];
  __shared__ int   zsh[NA];
  __shared__ float red[NWAVE];

  const int b   = blockIdx.x;
  const int tid = threadIdx.x;
  const int a16 = tid >> 6;
  const int g   = tid & 63;

  if (tid < NA) {
    zsh[tid]     = Z[b*NA + tid];
    posb[tid][0] = pos[(b*NA + tid)*3 + 0];
    posb[tid][1] = pos[(b*NA + tid)*3 + 1];
    posb[tid][2] = pos[(b*NA + tid)*3 + 2];
  }
  const float efx = Ef[b*3+0], efy = Ef[b*3+1], efz = Ef[b*3+2];
  __syncthreads();

  // init x: scalar-regular = embed[Z], rest 0
  #pragma unroll
  for (int t = 0; t < 2; ++t) {
    const int n = a16 + 16*t;
    if (n < NA) {
      xs[n][0][g] = embed[zsh[n]*FD + g];
      #pragma unroll
      for (int pc = 1; pc < 8; ++pc) xs[n][pc][g] = 0.0f;
    }
  }
  // unit vectors for all 812 (dst=i, src=j) pairs: disp = pos[j]-pos[i]
  for (int le = tid; le < NEDGE; le += TPB) {
    const int i  = le / 28;
    const int jr = le - i*28;
    const int j  = jr + (jr >= i ? 1 : 0);
    const float dx = posb[j][0] - posb[i][0];
    const float dy = posb[j][1] - posb[i][1];
    const float dz = posb[j][2] - posb[i][2];
    const float ri = 1.0f / sqrtf(dx*dx + dy*dy + dz*dz + 1e-12f);
    us[le][0] = dx*ri; us[le][1] = dy*ri; us[le][2] = dz*ri;
  }
  __syncthreads();

  float ya[2][8];

  #pragma unroll
  for (int it = 0; it < NITERS; ++it) {
    // ================= P1: message aggregation: y[n] = sum_j msg(x[j] -> n)
    const float* wmv = mp_tp_w + it*20*FD;
    float wm[10];
    #pragma unroll
    for (int q = 0; q < 5; ++q) { wm[q] = wmv[q*FD + g]; wm[5+q] = wmv[(10+q)*FD + g]; }
    #pragma unroll
    for (int t = 0; t < 2; ++t)
      #pragma unroll
      for (int pc = 0; pc < 8; ++pc) ya[t][pc] = 0.0f;

    const float* rpTit = rpT + (size_t)it*RPROJ_PLANE + (size_t)b*NA*64*28;
    const bool   last  = (it == NITERS-1);

    #pragma unroll
    for (int t = 0; t < 2; ++t) {
      const int n = a16 + 16*t;
      if (n >= NA) continue;
      // this row's 28 edge projections: contiguous 112 B -> 7 float4, all in flight
      float rpa[28];
      {
        const float* basep = rpTit + ((size_t)n*64 + g)*28;
        #pragma unroll
        for (int q = 0; q < 7; ++q) {
          const float4 v = *(const float4*)&basep[q*4];
          rpa[q*4+0] = v.x; rpa[q*4+1] = v.y; rpa[q*4+2] = v.z; rpa[q*4+3] = v.w;
        }
      }
      #pragma unroll
      for (int jr = 0; jr < 28; ++jr) {
        const int j  = jr + (jr >= n ? 1 : 0);
        const int le = n*28 + jr;
        const float s1  = xs[j][0][g], v1x = xs[j][1][g], v1y = xs[j][2][g], v1z = xs[j][3][g];
        const float s1p = xs[j][4][g], q1x = xs[j][5][g], q1y = xs[j][6][g], q1z = xs[j][7][g];
        const float ux = us[le][0], uy = us[le][1], uz = us[le][2];
        const float rp = rpa[jr];
        const float dot1 = v1x*ux + v1y*uy + v1z*uz;
        const float dotp = q1x*ux + q1y*uy + q1z*uz;
        ya[t][0] += rp*(wm[0]*s1  + wm[3]*dot1);
        ya[t][4] += rp*(wm[5]*s1p + wm[8]*dotp);
        if (!last) {
          const float c1x = v1y*uz - v1z*uy, c1y = v1z*ux - v1x*uz, c1z = v1x*uy - v1y*ux;
          const float cpx = q1y*uz - q1z*uy, cpy = q1z*ux - q1x*uz, cpz = q1x*uy - q1y*ux;
          const float aa = wm[1]*s1, bbp = wm[6]*s1p;
          ya[t][1] += rp*(aa*ux + wm[2]*v1x + wm[9]*cpx);
          ya[t][2] += rp*(aa*uy + wm[2]*v1y + wm[9]*cpy);
          ya[t][3] += rp*(aa*uz + wm[2]*v1z + wm[9]*cpz);
          ya[t][5] += rp*(bbp*ux + wm[7]*q1x + wm[4]*c1x);
          ya[t][6] += rp*(bbp*uy + wm[7]*q1y + wm[4]*c1y);
          ya[t][7] += rp*(bbp*uz + wm[7]*q1z + wm[4]*c1z);
        }
      }
    }
    __syncthreads();               // all reads of xs done before updates

    // x1 = x + y (register y; wave-local rows)
    #pragma unroll
    for (int t = 0; t < 2; ++t) {
      const int n = a16 + 16*t;
      if (n < NA) {
        #pragma unroll
        for (int pc = 0; pc < 8; ++pc) xs[n][pc][g] += ya[t][pc];
      }
    }

    // ================= P2: h = silu(d1(x1)) -> ts
    {
      float hr[2][8];
      dense29T(xs, WT + (0*8 + it*4)*4096, d1b + it*2*64, a16, g, hr);
      #pragma unroll
      for (int t = 0; t < 2; ++t) {
        const int n = a16 + 16*t;
        if (n >= NA) continue;
        #pragma unroll
        for (int p = 0; p < 2; ++p) {
          const float sv = hr[t][p*4];
          const float sg = 1.0f / (1.0f + expf(-sv));
          ts[n][p*4+0][g] = sv*sg;
          ts[n][p*4+1][g] = hr[t][p*4+1]*sg;
          ts[n][p*4+2][g] = hr[t][p*4+2]*sg;
          ts[n][p*4+3][g] = hr[t][p*4+3]*sg;
        }
      }
    }

    // ================= P3: x2 = d2(h)+y ; x3 = x2 + tp(x2, xEF, tens_w) -> xs (+regs)
    float x3r[2][8];
    {
      float h2[2][8];
      dense29T(ts, WT + (1*8 + it*4)*4096, d2b + it*2*64, a16, g, h2);
      float w20[20];
      #pragma unroll
      for (int q = 0; q < 20; ++q) w20[q] = tens_w[(it*20+q)*FD + g];
      const float bbv[8] = {1.0f, efx, efy, efz, 1.0f, efx, efy, efz};
      #pragma unroll
      for (int t = 0; t < 2; ++t) {
        const int n = a16 + 16*t;
        if (n >= NA) continue;
        float x2v[8], o[8];
        #pragma unroll
        for (int pc = 0; pc < 8; ++pc) { x2v[pc] = h2[t][pc] + ya[t][pc]; o[pc] = 0.0f; }
        tp20(x2v, bbv, w20, o);
        #pragma unroll
        for (int pc = 0; pc < 8; ++pc) {
          const float v = x2v[pc] + o[pc];
          x3r[t][pc] = v;
          xs[n][pc][g] = v;
        }
      }
    }

    // ================= P4+P5: td = dense(x3, tdw); x4 = tp(x3, td, td_tp_w) -> xs
    // Last iteration: only the scalar-regular output (o[0]) is ever consumed.
    {
      float td[2][8];
      dense29T(xs, WT + (2*8 + it*4)*4096, nullptr, a16, g, td);
      float w20[20];
      #pragma unroll
      for (int q = 0; q < 20; ++q) w20[q] = td_tp_w[(it*20+q)*FD + g];
      #pragma unroll
      for (int t = 0; t < 2; ++t) {
        const int n = a16 + 16*t;
        if (n >= NA) continue;
        if (it == NITERS-1) {
          // paths with dest sr: (p1,p2)=(0,0): w[0],w[3]; (1,1): w[15],w[18]
          const float o0 =
              w20[0]*(x3r[t][0]*td[t][0]) +
              w20[3]*(x3r[t][1]*td[t][1] + x3r[t][2]*td[t][2] + x3r[t][3]*td[t][3]) +
              w20[15]*(x3r[t][4]*td[t][4]) +
              w20[18]*(x3r[t][5]*td[t][5] + x3r[t][6]*td[t][6] + x3r[t][7]*td[t][7]);
          xs[n][0][g] = o0;
        } else {
          float o[8];
          #pragma unroll
          for (int pc = 0; pc < 8; ++pc) o[pc] = 0.0f;
          tp20(x3r[t], td[t], w20, o);
          #pragma unroll
          for (int pc = 0; pc < 8; ++pc) xs[n][pc][g] = o[pc];
        }
      }
    }
    __syncthreads();               // xs consistent for next iteration / output
  }

  // ================= energy: sum_n ( x[n,0,0,:] . out_w + ebias[Z[n]] )
  const float owg = out_w[g];
  float part = 0.0f;
  #pragma unroll
  for (int t = 0; t < 2; ++t) {
    const int n = a16 + 16*t;
    if (n < NA) part += xs[n][0][g] * owg;
  }
  #pragma unroll
  for (int off = 32; off > 0; off >>= 1) part += __shfl_xor(part, off, 64);
  if (g == 0) red[a16] = part;
  __syncthreads();
  if (tid == 0) {
    float s = 0.0f;
    #pragma unroll
    for (int q = 0; q < NWAVE; ++q) s += red[q];
    float be = 0.0f;
    for (int n = 0; n < NA; ++n) be += ebias[zsh[n]];
    out[b] = s + be;
  }
}

// ---------------------------------------------------------------------------
extern "C" void kernel_launch(void* const* d_in, const int* in_sizes, int n_in,
                              void* d_out, int out_size, void* d_ws, size_t ws_size,
                              hipStream_t stream)
{
  (void)in_sizes; (void)n_in; (void)out_size; (void)ws_size;
  const int*   Z     = (const int*)  d_in[0];
  const float* pos   = (const float*)d_in[1];
  const float* Ef    = (const float*)d_in[2];
  // d_in[3]/d_in[4] (dst_idx/src_idx): full i!=j meshgrid, reproduced analytically.
  const float* embed = (const float*)d_in[5];
  const float* mpbw  = (const float*)d_in[6];
  const float* mptpw = (const float*)d_in[7];
  const float* d1w   = (const float*)d_in[8];
  const float* d1b   = (const float*)d_in[9];
  const float* d2w   = (const float*)d_in[10];
  const float* d2b   = (const float*)d_in[11];
  const float* tensw = (const float*)d_in[12];
  const float* tdw   = (const float*)d_in[13];
  const float* tdtpw = (const float*)d_in[14];
  const float* outw  = (const float*)d_in[15];
  const float* ebias = (const float*)d_in[16];

  float* rpT = (float*)d_ws;
  float* WT  = (float*)d_ws + WT_OFF;

  transpose_w_kernel<<<384, 256, 0, stream>>>(d1w, d2w, tdw, WT);
  edge_rproj_kernel<<<NB*NA, 256, 0, stream>>>(pos, mpbw, rpT);
  fused_model_kernel<<<NB, TPB, 0, stream>>>(Z, pos, Ef, embed, mptpw,
      WT, d1b, d2b, tensw, tdtpw, outw, ebias, rpT, (float*)d_out);
}

// Round 5
// 241.349 us; speedup vs baseline: 9.5775x; 9.5775x over previous
//
#include <hip/hip_runtime.h>

// Problem constants (from reference setup)
#define NB 128            // batches
#define NA 29             // atoms per batch
#define BN (NB*NA)        // 3712 nodes
#define FD 64             // feature dim
#define RPLANE (BN*64*28) // one iteration's edge projections: 6,651,904 floats

// ws layout (floats): rpT[RPLANE] | x[BN*512] | y[BN*512]  -> 41.8 MB total
// (proven available: round 1 successfully used 53.2 MB of d_ws)

// ---------------------------------------------------------------------------
// Kernel A: one block per (batch,dst) node; 28 edges; radial basis projected
// through ONE iteration's mp_basis_w slice. Writes rp[(bn*64+g)*28 + jr]
// (jr-minor => msg kernels load each row's 28 values as 7 float4).
// Also zeroes d_out when outz != null (stream-ordered before the atomics).
// ---------------------------------------------------------------------------
__global__ __launch_bounds__(256) void edge_rproj_kernel(
    const float* __restrict__ pos,      // [BN][3]
    const float* __restrict__ Wb,      // [64][64] (iteration slice)
    float* __restrict__ rp,
    float* __restrict__ outz)
{
  __shared__ float elu[28], el1mu[28], efc[28];
  __shared__ float rads[28][FD];
  const int bn = blockIdx.x, b = bn / NA, n = bn - b*NA;
  const int tid = threadIdx.x, lane = tid & 63, wv = tid >> 6;

  if (outz != nullptr && bn == 0 && tid < NB) outz[tid] = 0.0f;

  if (tid < 28) {
    const int jr = tid, j = jr + (jr >= n ? 1 : 0);
    const float dx = pos[(b*NA+j)*3+0] - pos[(b*NA+n)*3+0];
    const float dy = pos[(b*NA+j)*3+1] - pos[(b*NA+n)*3+1];
    const float dz = pos[(b*NA+j)*3+2] - pos[(b*NA+n)*3+2];
    const float r  = sqrtf(dx*dx + dy*dy + dz*dz + 1e-12f);
    const float u  = 1.0f/(1.0f + r);
    elu[jr]   = logf(u);
    el1mu[jr] = logf(fmaxf(1.0f - u, 1e-12f));
    const float x2 = (r*0.2f)*(r*0.2f);
    efc[jr] = (x2 < 1.0f) ? expf(1.0f - 1.0f/fmaxf(1.0f - x2, 1e-12f)) : 0.0f;
  }
  const float kk   = (float)lane;
  const float logc = lgammaf(64.0f) - lgammaf(kk + 1.0f) - lgammaf(64.0f - kk);
  __syncthreads();                      // elu/el1mu/efc shared across waves

  #pragma unroll
  for (int i = 0; i < 7; ++i) {         // wave-private rows: no barrier below
    const int e = wv*7 + i;
    rads[e][lane] = expf(logc + kk*elu[e] + (63.0f - kk)*el1mu[e]) * efc[e];
  }
  float wb[64];
  #pragma unroll
  for (int k = 0; k < 64; ++k) wb[k] = Wb[k*FD + lane];

  #pragma unroll
  for (int i = 0; i < 7; ++i) {
    const int jr = wv*7 + i;
    float a0 = 0.0f;
    #pragma unroll
    for (int k4 = 0; k4 < 16; ++k4) {
      const float4 rv = *(const float4*)&rads[jr][k4*4];  // same-wave RAW
      a0 += wb[k4*4+0]*rv.x + wb[k4*4+1]*rv.y + wb[k4*4+2]*rv.z + wb[k4*4+3]*rv.w;
    }
    rp[((size_t)bn*64 + lane)*28 + jr] = a0;
  }
}

// ---------------------------------------------------------------------------
// Kernel B: iteration-0 messages. x0 has ONLY scalar-regular = embed[Z], so
// per edge: sr += rp*w0*s1 ; vr += rp*w1*s1*u ; pseudo outputs are all zero.
// Grid: (batch,shard) = 128*4 blocks, 512 threads; thread (r=tid>>6,g) owns
// dst row n = shard*8+r, feature g.
// ---------------------------------------------------------------------------
__global__ __launch_bounds__(512) void msg0_kernel(
    const int*   __restrict__ Z,
    const float* __restrict__ pos,
    const float* __restrict__ embed,
    const float* __restrict__ wtp,      // mp_tp_w[0] : [20][64]
    const float* __restrict__ rp,
    float* __restrict__ y)              // [BN][8][64]
{
  __shared__ float emb_sh[NA][FD];
  __shared__ float posb[NA][3];
  __shared__ float us_sh[8][28][3];
  const int bi = blockIdx.x, b = bi >> 2, shard = bi & 3;
  const int tid = threadIdx.x, r = tid >> 6, g = tid & 63;

  if (tid < NA) {
    posb[tid][0] = pos[(b*NA+tid)*3+0];
    posb[tid][1] = pos[(b*NA+tid)*3+1];
    posb[tid][2] = pos[(b*NA+tid)*3+2];
  }
  __syncthreads();
  for (int idx = tid; idx < NA*FD; idx += 512)
    emb_sh[idx>>6][idx&63] = embed[Z[b*NA + (idx>>6)]*FD + (idx&63)];
  if (tid < 224) {
    const int rr = tid/28, jr = tid - rr*28, nn = shard*8 + rr;
    if (nn < NA) {
      const int j = jr + (jr >= nn ? 1 : 0);
      const float dx = posb[j][0]-posb[nn][0];
      const float dy = posb[j][1]-posb[nn][1];
      const float dz = posb[j][2]-posb[nn][2];
      const float ri = 1.0f / sqrtf(dx*dx + dy*dy + dz*dz + 1e-12f);
      us_sh[rr][jr][0] = dx*ri; us_sh[rr][jr][1] = dy*ri; us_sh[rr][jr][2] = dz*ri;
    }
  }
  __syncthreads();

  const int n = shard*8 + r;
  if (n >= NA) return;
  const int bn = b*NA + n;
  const float wm0 = wtp[0*FD + g], wm1 = wtp[1*FD + g];

  float rpa[28];
  {
    const float4* bp = (const float4*)(rp + ((size_t)bn*64 + g)*28);
    #pragma unroll
    for (int q = 0; q < 7; ++q) {
      const float4 v = bp[q];
      rpa[q*4+0] = v.x; rpa[q*4+1] = v.y; rpa[q*4+2] = v.z; rpa[q*4+3] = v.w;
    }
  }
  float y0 = 0.0f, y1 = 0.0f, y2 = 0.0f, y3 = 0.0f;
  #pragma unroll
  for (int jr = 0; jr < 28; ++jr) {
    const int j = jr + (jr >= n ? 1 : 0);
    const float t0 = rpa[jr] * emb_sh[j][g];
    y0 += wm0*t0;
    const float t1 = wm1*t0;
    y1 += t1*us_sh[r][jr][0];
    y2 += t1*us_sh[r][jr][1];
    y3 += t1*us_sh[r][jr][2];
  }
  float* yb = y + (size_t)bn*512 + g;
  yb[0] = y0; yb[64] = y1; yb[128] = y2; yb[192] = y3;
  yb[256] = 0.0f; yb[320] = 0.0f; yb[384] = 0.0f; yb[448] = 0.0f;
}

// ---------------------------------------------------------------------------
// Kernel D: iteration-1 messages from full x; last-iteration channel mask
// [1,0,0,0] keeps only the two parity scalars -> write y0, y4 only.
// ---------------------------------------------------------------------------
__global__ __launch_bounds__(512) void msg1_kernel(
    const float* __restrict__ pos,
    const float* __restrict__ wtp,      // mp_tp_w[1] : [20][64]
    const float* __restrict__ rp,
    const float* __restrict__ x,        // [BN][8][64]
    float* __restrict__ y)
{
  __shared__ float x_sh[NA][8][FD];     // 59392 B
  __shared__ float posb[NA][3];
  __shared__ float us_sh[8][28][3];
  const int bi = blockIdx.x, b = bi >> 2, shard = bi & 3;
  const int tid = threadIdx.x, r = tid >> 6, g = tid & 63;

  if (tid < NA) {
    posb[tid][0] = pos[(b*NA+tid)*3+0];
    posb[tid][1] = pos[(b*NA+tid)*3+1];
    posb[tid][2] = pos[(b*NA+tid)*3+2];
  }
  __syncthreads();
  {
    float4* dst = (float4*)&x_sh[0][0][0];
    const float4* src = (const float4*)(x + (size_t)b*NA*512);
    for (int i = tid; i < NA*512/4; i += 512) dst[i] = src[i];
  }
  if (tid < 224) {
    const int rr = tid/28, jr = tid - rr*28, nn = shard*8 + rr;
    if (nn < NA) {
      const int j = jr + (jr >= nn ? 1 : 0);
      const float dx = posb[j][0]-posb[nn][0];
      const float dy = posb[j][1]-posb[nn][1];
      const float dz = posb[j][2]-posb[nn][2];
      const float ri = 1.0f / sqrtf(dx*dx + dy*dy + dz*dz + 1e-12f);
      us_sh[rr][jr][0] = dx*ri; us_sh[rr][jr][1] = dy*ri; us_sh[rr][jr][2] = dz*ri;
    }
  }
  __syncthreads();

  const int n = shard*8 + r;
  if (n >= NA) return;
  const int bn = b*NA + n;
  const float wm0 = wtp[0*FD+g], wm3 = wtp[3*FD+g];
  const float wm5 = wtp[10*FD+g], wm8 = wtp[13*FD+g];

  float rpa[28];
  {
    const float4* bp = (const float4*)(rp + ((size_t)bn*64 + g)*28);
    #pragma unroll
    for (int q = 0; q < 7; ++q) {
      const float4 v = bp[q];
      rpa[q*4+0] = v.x; rpa[q*4+1] = v.y; rpa[q*4+2] = v.z; rpa[q*4+3] = v.w;
    }
  }
  float y0 = 0.0f, y4 = 0.0f;
  #pragma unroll
  for (int jr = 0; jr < 28; ++jr) {
    const int j = jr + (jr >= n ? 1 : 0);
    const float ux = us_sh[r][jr][0], uy = us_sh[r][jr][1], uz = us_sh[r][jr][2];
    const float s1  = x_sh[j][0][g];
    const float dot1 = x_sh[j][1][g]*ux + x_sh[j][2][g]*uy + x_sh[j][3][g]*uz;
    const float s1p = x_sh[j][4][g];
    const float dotp = x_sh[j][5][g]*ux + x_sh[j][6][g]*uy + x_sh[j][7][g]*uz;
    y0 += rpa[jr]*(wm0*s1  + wm3*dot1);
    y4 += rpa[jr]*(wm5*s1p + wm8*dotp);
  }
  y[(size_t)bn*512 + g]       = y0;
  y[(size_t)bn*512 + 256 + g] = y4;
}

// ---------------------------------------------------------------------------
// 20-path Clebsch-Gordan tensor product at one feature index.
// ---------------------------------------------------------------------------
__device__ __forceinline__ void tp20(const float* a, const float* bb,
                                     const float* w, float* o)
{
  #pragma unroll
  for (int p1 = 0; p1 < 2; ++p1) {
    #pragma unroll
    for (int p2 = 0; p2 < 2; ++p2) {
      const float* w5 = w + 5*(2*p1 + p2);
      const float s1 = a[p1*4+0], x1 = a[p1*4+1], y1 = a[p1*4+2], z1 = a[p1*4+3];
      const float s2 = bb[p2*4+0], x2 = bb[p2*4+1], y2 = bb[p2*4+2], z2 = bb[p2*4+3];
      const int so = (p1 == p2) ? 0 : 4;   // dest parity for T1..T4
      const int vo = 4 - so;               // dest parity for T5 (cross)
      o[so+0] += w5[0]*(s1*s2) + w5[3]*(x1*x2 + y1*y2 + z1*z2);
      o[so+1] += w5[1]*(s1*x2) + w5[2]*(x1*s2);
      o[so+2] += w5[1]*(s1*y2) + w5[2]*(y1*s2);
      o[so+3] += w5[1]*(s1*z2) + w5[2]*(z1*s2);
      o[vo+1] += w5[4]*(y1*z2 - z1*y2);
      o[vo+2] += w5[4]*(z1*x2 - x1*z2);
      o[vo+3] += w5[4]*(x1*y2 - y1*x2);
    }
  }
}

// ---------------------------------------------------------------------------
// Per-node dense (one node per WAVE): input row lives in this wave's private
// LDS row (broadcast float4 reads); weights are f-outer coalesced scalar
// loads from the ORIGINAL [p][sel][f][g] layout (L2-hot, 256B/lane-row).
// ---------------------------------------------------------------------------
__device__ __forceinline__ void denseRow(const float* __restrict__ in,
                                         const float* __restrict__ W,
                                         const float* __restrict__ bias,
                                         int g, float o[8])
{
  #pragma unroll
  for (int p = 0; p < 2; ++p) {
    {
      const float* Wp = W + (p*2+0)*4096 + g;
      float acc = bias ? bias[p*64 + g] : 0.0f;
      #pragma unroll
      for (int f4 = 0; f4 < 16; ++f4) {
        const float w0 = Wp[(f4*4+0)*64], w1 = Wp[(f4*4+1)*64];
        const float w2 = Wp[(f4*4+2)*64], w3 = Wp[(f4*4+3)*64];
        const float4 xv = *(const float4*)&in[(p*4+0)*64 + f4*4];
        acc += w0*xv.x + w1*xv.y + w2*xv.z + w3*xv.w;
      }
      o[p*4+0] = acc;
    }
    {
      const float* Wp = W + (p*2+1)*4096 + g;
      float a1 = 0.0f, a2 = 0.0f, a3 = 0.0f;
      #pragma unroll
      for (int f4 = 0; f4 < 16; ++f4) {
        const float w0 = Wp[(f4*4+0)*64], w1 = Wp[(f4*4+1)*64];
        const float w2 = Wp[(f4*4+2)*64], w3 = Wp[(f4*4+3)*64];
        const float4 xa = *(const float4*)&in[(p*4+1)*64 + f4*4];
        const float4 xb = *(const float4*)&in[(p*4+2)*64 + f4*4];
        const float4 xc = *(const float4*)&in[(p*4+3)*64 + f4*4];
        a1 += w0*xa.x + w1*xa.y + w2*xa.z + w3*xa.w;
        a2 += w0*xb.x + w1*xb.y + w2*xb.z + w3*xb.w;
        a3 += w0*xc.x + w1*xc.y + w2*xc.z + w3*xc.w;
      }
      o[p*4+1] = a1; o[p*4+2] = a2; o[p*4+3] = a3;
    }
  }
}

// ---------------------------------------------------------------------------
// Kernel C/E: all per-node phases for one iteration. One node per wave,
// 4 nodes per 256-thread block, grid 928 -> all 256 CUs busy, no barriers
// (each wave's LDS row is private). Weight pointers are pre-offset to the
// iteration slice. LAST: trimmed tail + energy atomicAdd.
// ---------------------------------------------------------------------------
template<bool LAST>
__global__ __launch_bounds__(256) void node_kernel(
    const int*   __restrict__ Z,
    const float* __restrict__ embed,
    const float* __restrict__ Ef,
    const float* __restrict__ d1w, const float* __restrict__ d1b,
    const float* __restrict__ d2w, const float* __restrict__ d2b,
    const float* __restrict__ tens_w,
    const float* __restrict__ tdw,
    const float* __restrict__ td_tp_w,
    const float* __restrict__ out_w,
    const float* __restrict__ ebias,
    const float* __restrict__ xin,      // LAST only
    const float* __restrict__ yin,
    float* __restrict__ xout,           // !LAST only
    float* __restrict__ out)            // LAST only
{
  __shared__ float row[4][8][FD];       // 8 KB; row[r] private to wave r
  const int tid = threadIdx.x, r = tid >> 6, g = tid & 63;
  const int nd = blockIdx.x*4 + r;      // BN = 928*4 exactly
  const int b  = nd / NA;
  float* myrow = &row[r][0][0];

  // ---- x1 = x + y
  float yv0, yv4, yvf[8];
  float x1[8];
  if constexpr (!LAST) {
    #pragma unroll
    for (int pc = 0; pc < 8; ++pc) yvf[pc] = yin[(size_t)nd*512 + pc*64 + g];
    x1[0] = embed[Z[nd]*FD + g] + yvf[0];
    #pragma unroll
    for (int pc = 1; pc < 8; ++pc) x1[pc] = yvf[pc];
    yv0 = yvf[0]; yv4 = yvf[4];
  } else {
    yv0 = yin[(size_t)nd*512 + g];
    yv4 = yin[(size_t)nd*512 + 256 + g];
    #pragma unroll
    for (int pc = 0; pc < 8; ++pc) {
      float v = xin[(size_t)nd*512 + pc*64 + g];
      if (pc == 0) v += yv0;
      if (pc == 4) v += yv4;
      x1[pc] = v;
    }
  }
  #pragma unroll
  for (int pc = 0; pc < 8; ++pc) myrow[pc*64 + g] = x1[pc];

  // ---- h = silu(d1(x1)) -> same LDS row (same-wave RAW, in-order ds ops)
  float hr[8];
  denseRow(myrow, d1w, d1b, g, hr);
  #pragma unroll
  for (int p = 0; p < 2; ++p) {
    const float sv = hr[p*4];
    const float sg = 1.0f / (1.0f + expf(-sv));
    myrow[(p*4+0)*64+g] = sv*sg;
    myrow[(p*4+1)*64+g] = hr[p*4+1]*sg;
    myrow[(p*4+2)*64+g] = hr[p*4+2]*sg;
    myrow[(p*4+3)*64+g] = hr[p*4+3]*sg;
  }

  // ---- x2 = d2(h) + y ; x3 = x2 + tp(x2, xEF, tens_w)
  float h2[8];
  denseRow(myrow, d2w, d2b, g, h2);
  float x2[8], x3[8];
  if constexpr (!LAST) {
    #pragma unroll
    for (int pc = 0; pc < 8; ++pc) x2[pc] = h2[pc] + yvf[pc];
  } else {
    #pragma unroll
    for (int pc = 0; pc < 8; ++pc) {
      float v = h2[pc];
      if (pc == 0) v += yv0;
      if (pc == 4) v += yv4;
      x2[pc] = v;
    }
  }
  {
    const float efx = Ef[b*3+0], efy = Ef[b*3+1], efz = Ef[b*3+2];
    const float bbv[8] = {1.0f, efx, efy, efz, 1.0f, efx, efy, efz};
    float w20[20];
    #pragma unroll
    for (int q = 0; q < 20; ++q) w20[q] = tens_w[q*FD + g];
    float o[8] = {0,0,0,0,0,0,0,0};
    tp20(x2, bbv, w20, o);
    #pragma unroll
    for (int pc = 0; pc < 8; ++pc) {
      x3[pc] = x2[pc] + o[pc];
      myrow[pc*64 + g] = x3[pc];
    }
  }

  // ---- td = dense(x3, tdw) ; x4 = tp(x3, td, td_tp_w)
  float td[8];
  denseRow(myrow, tdw, nullptr, g, td);
  if constexpr (LAST) {
    // only scalar-regular output feeds the energy:
    // paths (p1,p2)=(0,0): w[0],w[3]; (1,1): w[15],w[18]
    const float wa = td_tp_w[0*FD+g],  wb = td_tp_w[3*FD+g];
    const float wc = td_tp_w[15*FD+g], wd = td_tp_w[18*FD+g];
    const float o0 = wa*(x3[0]*td[0])
                   + wb*(x3[1]*td[1] + x3[2]*td[2] + x3[3]*td[3])
                   + wc*(x3[4]*td[4])
                   + wd*(x3[5]*td[5] + x3[6]*td[6] + x3[7]*td[7]);
    float part = o0 * out_w[g];
    #pragma unroll
    for (int off = 32; off > 0; off >>= 1) part += __shfl_xor(part, off, 64);
    if (g == 0) atomicAdd(&out[b], part + ebias[Z[nd]]);
  } else {
    float w20[20];
    #pragma unroll
    for (int q = 0; q < 20; ++q) w20[q] = td_tp_w[q*FD + g];
    float o[8] = {0,0,0,0,0,0,0,0};
    tp20(x3, td, w20, o);
    #pragma unroll
    for (int pc = 0; pc < 8; ++pc) xout[(size_t)nd*512 + pc*64 + g] = o[pc];
  }
}

// ---------------------------------------------------------------------------
extern "C" void kernel_launch(void* const* d_in, const int* in_sizes, int n_in,
                              void* d_out, int out_size, void* d_ws, size_t ws_size,
                              hipStream_t stream)
{
  (void)in_sizes; (void)n_in; (void)out_size; (void)ws_size;
  const int*   Z     = (const int*)  d_in[0];
  const float* pos   = (const float*)d_in[1];
  const float* Ef    = (const float*)d_in[2];
  // d_in[3]/d_in[4] (dst_idx/src_idx): full i!=j meshgrid, reproduced analytically.
  const float* embed = (const float*)d_in[5];
  const float* mpbw  = (const float*)d_in[6];
  const float* mptpw = (const float*)d_in[7];
  const float* d1w   = (const float*)d_in[8];
  const float* d1b   = (const float*)d_in[9];
  const float* d2w   = (const float*)d_in[10];
  const float* d2b   = (const float*)d_in[11];
  const float* tensw = (const float*)d_in[12];
  const float* tdw   = (const float*)d_in[13];
  const float* tdtpw = (const float*)d_in[14];
  const float* outw  = (const float*)d_in[15];
  const float* ebias = (const float*)d_in[16];
  float* out = (float*)d_out;

  float* rpT = (float*)d_ws;                 // RPLANE floats (reused per iter)
  float* xg  = rpT + RPLANE;                 // BN*512
  float* yg  = xg + (size_t)BN*512;          // BN*512

  // it = 0
  edge_rproj_kernel<<<BN, 256, 0, stream>>>(pos, mpbw, rpT, out);   // + zero out
  msg0_kernel<<<NB*4, 512, 0, stream>>>(Z, pos, embed, mptpw, rpT, yg);
  node_kernel<false><<<BN/4, 256, 0, stream>>>(Z, embed, Ef,
      d1w, d1b, d2w, d2b, tensw, tdw, tdtpw, outw, ebias,
      nullptr, yg, xg, nullptr);
  // it = 1 (rpT buffer reused; stream order guarantees msg0 is done with it)
  edge_rproj_kernel<<<BN, 256, 0, stream>>>(pos, mpbw + 4096, rpT, nullptr);
  msg1_kernel<<<NB*4, 512, 0, stream>>>(pos, mptpw + 20*64, rpT, xg, yg);
  node_kernel<true><<<BN/4, 256, 0, stream>>>(Z, embed, Ef,
      d1w + 16384, d1b + 128, d2w + 16384, d2b + 128, tensw + 20*64,
      tdw + 16384, tdtpw + 20*64, outw, ebias,
      xg, yg, nullptr, out);
}